// Round 1
// baseline (496.621 us; speedup 1.0000x reference)
//
#include <hip/hip_runtime.h>

#define NUM_EMB 1024
#define EDIM 64
#define HW 4096      // 64*64 spatial
#define CHW 262144   // 64 channels * 4096
#define NPOS 65536   // 16 * 4096 positions
#define NOUT 4194304 // 16*64*64*64 output elements (excl. loss scalar)

// Kernel 1: codebook squared norms into ws, zero the loss accumulator.
__global__ void vq_norms_kernel(const float* __restrict__ emb,
                                float* __restrict__ norms,
                                float* __restrict__ loss_out) {
    int k = blockIdx.x * blockDim.x + threadIdx.x;
    if (k == 0) *loss_out = 0.0f;
    if (k < NUM_EMB) {
        const float* e = emb + k * EDIM;
        float s = 0.0f;
#pragma unroll
        for (int c = 0; c < EDIM; ++c) s = fmaf(e[c], e[c], s);
        norms[k] = s;
    }
}

// Kernel 2: per position, argmin over codes; write quantized [B,C,H,W]; loss.
__global__ __launch_bounds__(256) void vq_main_kernel(
        const float* __restrict__ inp,
        const float* __restrict__ emb,
        const float* __restrict__ norms,
        float* __restrict__ out,
        float* __restrict__ loss_out) {
    const int n  = blockIdx.x * 256 + threadIdx.x;   // position id
    const int b  = n >> 12;                           // n / 4096
    const int hw = n & 4095;

    // Load x[64] into registers. For fixed c, consecutive threads read
    // consecutive addresses -> fully coalesced.
    const float* xin = inp + b * CHW + hw;
    float x[EDIM];
#pragma unroll
    for (int c = 0; c < EDIM; ++c) x[c] = xin[c * HW];

    // argmin_k ( ||e_k||^2 - 2 x.e_k )  — ||x||^2 is constant per row.
    float best = 3.4e38f;
    int bestk = 0;
    for (int k = 0; k < NUM_EMB; ++k) {
        // Wave-uniform address -> scalar loads (SGPR broadcast operands).
        const float* e = emb + (k << 6);
        float d0 = 0.f, d1 = 0.f, d2 = 0.f, d3 = 0.f;
#pragma unroll
        for (int c = 0; c < EDIM; c += 4) {
            d0 = fmaf(x[c + 0], e[c + 0], d0);
            d1 = fmaf(x[c + 1], e[c + 1], d1);
            d2 = fmaf(x[c + 2], e[c + 2], d2);
            d3 = fmaf(x[c + 3], e[c + 3], d3);
        }
        float score = norms[k] - 2.0f * ((d0 + d1) + (d2 + d3));
        if (score < best) { best = score; bestk = k; }   // strict < == first min
    }

    // Gather winning code (per-thread contiguous, float4), write [B,C,H,W],
    // accumulate squared error.
    const float4* e4 = reinterpret_cast<const float4*>(emb + (bestk << 6));
    float* o = out + b * CHW + hw;
    float part = 0.0f;
#pragma unroll
    for (int c4 = 0; c4 < EDIM / 4; ++c4) {
        float4 q = e4[c4];
        int c = c4 * 4;
        float dd;
        dd = q.x - x[c + 0]; part = fmaf(dd, dd, part); o[(c + 0) * HW] = q.x;
        dd = q.y - x[c + 1]; part = fmaf(dd, dd, part); o[(c + 1) * HW] = q.y;
        dd = q.z - x[c + 2]; part = fmaf(dd, dd, part); o[(c + 2) * HW] = q.z;
        dd = q.w - x[c + 3]; part = fmaf(dd, dd, part); o[(c + 3) * HW] = q.w;
    }

    // Loss reduction: wave shuffle (width 64) -> LDS -> one atomic per block.
#pragma unroll
    for (int off = 32; off > 0; off >>= 1)
        part += __shfl_down(part, off, 64);
    __shared__ float wsum[4];
    const int lane = threadIdx.x & 63;
    const int wv   = threadIdx.x >> 6;
    if (lane == 0) wsum[wv] = part;
    __syncthreads();
    if (threadIdx.x == 0) {
        float s = (wsum[0] + wsum[1]) + (wsum[2] + wsum[3]);
        // loss = (1 + 0.25) * mean((q - x)^2)
        atomicAdd(loss_out, s * (1.25f / (float)NOUT));
    }
}

extern "C" void kernel_launch(void* const* d_in, const int* in_sizes, int n_in,
                              void* d_out, int out_size, void* d_ws, size_t ws_size,
                              hipStream_t stream) {
    const float* inp  = (const float*)d_in[0];   // [16,64,64,64] fp32
    const float* emb  = (const float*)d_in[1];   // [1024,64] fp32
    float* out  = (float*)d_out;                 // 4194304 quantized + 1 loss
    float* norms = (float*)d_ws;                 // 1024 floats scratch
    float* loss = out + NOUT;

    vq_norms_kernel<<<NUM_EMB / 256, 256, 0, stream>>>(emb, norms, loss);
    vq_main_kernel<<<NPOS / 256, 256, 0, stream>>>(inp, emb, norms, out, loss);
}

// Round 2
// 107.383 us; speedup vs baseline: 4.6248x; 4.6248x over previous
//
#include <hip/hip_runtime.h>

#define NUM_EMB 1024
#define EDIM 64
#define HW 4096      // 64*64 spatial
#define CHW 262144   // 64 ch * 4096
#define NPOS 65536   // 16 * 4096 positions
#define NOUT 4194304 // output elements (excl. loss scalar)

typedef __attribute__((ext_vector_type(8))) short short8;   // 8 bf16 = 4 VGPRs
typedef __attribute__((ext_vector_type(4))) float f32x4;

__device__ inline short f32_to_bf16_rne(float f) {
    unsigned u = __float_as_uint(f);
    unsigned r = (u + 0x7fffu + ((u >> 16) & 1u)) >> 16;
    return (short)r;
}

// Prep: codebook -> bf16 pre-swizzled into MFMA B-fragment order, half-norms,
// and zero the loss accumulator. B-frag layout (16x16x32): lane = (n&15)|(quad<<4)
// holds B[n][k = chunk*32 + quad*8 + j], j=0..7 contiguous -> dwordx4 loads.
__global__ void vq_prep_kernel(const float* __restrict__ emb,
                               short* __restrict__ bsw,
                               float* __restrict__ hn,
                               float* __restrict__ loss_out) {
    int k = blockIdx.x * blockDim.x + threadIdx.x;   // code id, 0..1023
    if (k == 0) *loss_out = 0.0f;
    const float* e = emb + k * EDIM;
    const int T = k >> 4, nl = k & 15;
    float s = 0.0f;
#pragma unroll
    for (int c = 0; c < EDIM; ++c) {
        float v = e[c];
        s = fmaf(v, v, s);
        int chunk = c >> 5;
        int quad  = (c >> 3) & 3;
        int j     = c & 7;
        int lane  = nl | (quad << 4);
        bsw[((T * 2 + chunk) * 64 + lane) * 8 + j] = f32_to_bf16_rne(v);
    }
    hn[k] = 0.5f * s;
}

// Main: per wave, 32 positions (2 M-tiles) x all 1024 codes via bf16 MFMA.
// score = 0.5*||e||^2 - x.e  (||x||^2 constant per row, dropped).
__global__ __launch_bounds__(256) void vq_mfma_kernel(
        const float* __restrict__ inp,
        const float* __restrict__ emb,
        const short* __restrict__ bsw,
        const float* __restrict__ hn,
        float* __restrict__ out,
        float* __restrict__ loss_out) {
    __shared__ int   s_idx[128];
    __shared__ float s_wsum[4];

    const int tid    = threadIdx.x;
    const int w      = tid >> 6;
    const int lane   = tid & 63;
    const int lanelo = lane & 15;
    const int quad   = lane >> 4;
    const int pb     = blockIdx.x * 128;   // block covers 128 contiguous positions

    // ---- A fragments: 2 M-tiles x 2 K-chunks. A[m=lane&15][k=quad*8+j]. ----
    short8 a[2][2];
#pragma unroll
    for (int t = 0; t < 2; ++t) {
        const int p  = pb + w * 32 + t * 16 + lanelo;
        const int b  = p >> 12, hw = p & 4095;
        const float* xp = inp + b * CHW + hw;
#pragma unroll
        for (int chunk = 0; chunk < 2; ++chunk)
#pragma unroll
            for (int j = 0; j < 8; ++j) {
                int c = chunk * 32 + quad * 8 + j;
                a[t][chunk][j] = f32_to_bf16_rne(xp[c * HW]);
            }
    }

    float best[2][4];
    int   bk[2][4];
#pragma unroll
    for (int t = 0; t < 2; ++t)
#pragma unroll
        for (int r = 0; r < 4; ++r) { best[t][r] = 3.4e38f; bk[t][r] = 0; }

    // ---- k-loop over 64 code tiles of 16 ----
#pragma unroll 4
    for (int T = 0; T < 64; ++T) {
        const short8 b0 = *(const short8*)(bsw + (T * 128 + lane) * 8);
        const short8 b1 = *(const short8*)(bsw + (T * 128 + 64 + lane) * 8);
        const int   kn = (T << 4) | lanelo;
        const float h  = hn[kn];
        f32x4 acc0 = {0.f, 0.f, 0.f, 0.f};
        f32x4 acc1 = {0.f, 0.f, 0.f, 0.f};
        acc0 = __builtin_amdgcn_mfma_f32_16x16x32_bf16(a[0][0], b0, acc0, 0, 0, 0);
        acc0 = __builtin_amdgcn_mfma_f32_16x16x32_bf16(a[0][1], b1, acc0, 0, 0, 0);
        acc1 = __builtin_amdgcn_mfma_f32_16x16x32_bf16(a[1][0], b0, acc1, 0, 0, 0);
        acc1 = __builtin_amdgcn_mfma_f32_16x16x32_bf16(a[1][1], b1, acc1, 0, 0, 0);
#pragma unroll
        for (int r = 0; r < 4; ++r) {
            float s0 = h - acc0[r];
            if (s0 < best[0][r]) { best[0][r] = s0; bk[0][r] = kn; }
            float s1 = h - acc1[r];
            if (s1 < best[1][r]) { best[1][r] = s1; bk[1][r] = kn; }
        }
    }

    // ---- cross-lane argmin: 16 lanes (same quad-group) hold a position's codes ----
#pragma unroll
    for (int t = 0; t < 2; ++t)
#pragma unroll
        for (int r = 0; r < 4; ++r) {
            float bs = best[t][r];
            int   bi = bk[t][r];
#pragma unroll
            for (int m = 1; m < 16; m <<= 1) {
                float os = __shfl_xor(bs, m, 64);
                int   oi = __shfl_xor(bi, m, 64);
                if (os < bs || (os == bs && oi < bi)) { bs = os; bi = oi; }
            }
            if (lanelo == 0)
                s_idx[w * 32 + t * 16 + quad * 4 + r] = bi;  // C/D row = quad*4+reg
        }
    __syncthreads();

    // ---- epilogue: gather exact fp32 code rows, write [B,C,H,W], loss ----
    const int pos = tid & 127;
    const int ch0 = (tid >> 7) * 32;
    const int p   = pb + pos;
    const int b   = p >> 12, hw = p & 4095;
    const int myk = s_idx[pos];
    const float4* er4 = reinterpret_cast<const float4*>(emb + myk * EDIM + ch0);
    const float*  xr  = inp + b * CHW + hw;
    float*        orow = out + b * CHW + hw;
    float part = 0.0f;
#pragma unroll
    for (int i4 = 0; i4 < 8; ++i4) {
        float4 q4 = er4[i4];
        int c = ch0 + i4 * 4;
        float d;
        d = q4.x - xr[(c + 0) * HW]; part = fmaf(d, d, part); orow[(c + 0) * HW] = q4.x;
        d = q4.y - xr[(c + 1) * HW]; part = fmaf(d, d, part); orow[(c + 1) * HW] = q4.y;
        d = q4.z - xr[(c + 2) * HW]; part = fmaf(d, d, part); orow[(c + 2) * HW] = q4.z;
        d = q4.w - xr[(c + 3) * HW]; part = fmaf(d, d, part); orow[(c + 3) * HW] = q4.w;
    }

    // loss: wave shuffle -> LDS -> one atomic per block
#pragma unroll
    for (int off = 32; off > 0; off >>= 1)
        part += __shfl_down(part, off, 64);
    if (lane == 0) s_wsum[w] = part;
    __syncthreads();
    if (tid == 0) {
        float s = (s_wsum[0] + s_wsum[1]) + (s_wsum[2] + s_wsum[3]);
        atomicAdd(loss_out, s * (1.25f / (float)NOUT));
    }
}

extern "C" void kernel_launch(void* const* d_in, const int* in_sizes, int n_in,
                              void* d_out, int out_size, void* d_ws, size_t ws_size,
                              hipStream_t stream) {
    const float* inp = (const float*)d_in[0];    // [16,64,64,64] fp32
    const float* emb = (const float*)d_in[1];    // [1024,64] fp32
    float* out = (float*)d_out;                  // 4194304 quantized + 1 loss
    float* loss = out + NOUT;

    short* bsw = (short*)d_ws;                           // 128 KiB bf16 swizzled B
    float* hn  = (float*)((char*)d_ws + 131072);         // 4 KiB half-norms

    vq_prep_kernel<<<NUM_EMB / 256, 256, 0, stream>>>(emb, bsw, hn, loss);
    vq_mfma_kernel<<<NPOS / 128, 256, 0, stream>>>(inp, emb, bsw, hn, out, loss);
}

// Round 3
// 95.913 us; speedup vs baseline: 5.1778x; 1.1196x over previous
//
#include <hip/hip_runtime.h>

#define NUM_EMB 1024
#define EDIM 64
#define HW 4096      // 64*64 spatial
#define CHW 262144   // 64 ch * 4096
#define NPOS 65536   // 16 * 4096 positions
#define NOUT 4194304 // output elements (excl. loss scalar)

typedef __attribute__((ext_vector_type(8))) short short8;   // 8 bf16 = 4 VGPRs
typedef __attribute__((ext_vector_type(4))) float f32x4;

__device__ inline short f32_to_bf16_rne(float f) {
    unsigned u = __float_as_uint(f);
    unsigned r = (u + 0x7fffu + ((u >> 16) & 1u)) >> 16;
    return (short)r;
}

// Prep: codebook -> bf16 swizzled B-fragments + biased half-norms + zero loss.
// 16384 threads: thread = (code k, 4-channel group). Coalesced float4 load,
// 16-lane shuffle reduce for the norm, one 8B store into the swizzled layout.
// B-frag (16x16x32): lane=(n&15)|(quad<<4) holds B[n][chunk*32+quad*8+j], j=0..7.
__global__ void vq_prep_kernel(const float* __restrict__ emb,
                               short* __restrict__ bsw,
                               float* __restrict__ hnb,
                               float* __restrict__ loss_out) {
    const int gid = blockIdx.x * 256 + threadIdx.x;   // 0..16383
    if (gid == 0) *loss_out = 0.0f;
    const int k  = gid >> 4;          // code id
    const int c0 = (gid & 15) * 4;    // channel group base
    float4 v = *(const float4*)(emb + k * EDIM + c0);
    float s = v.x * v.x + v.y * v.y + v.z * v.z + v.w * v.w;
#pragma unroll
    for (int m = 1; m < 16; m <<= 1) s += __shfl_xor(s, m, 64);
    if (c0 == 0) hnb[k] = 0.5f * s + 0.25f;           // bias -> scores positive

    const int T = k >> 4, nl = k & 15;
    const int chunk = c0 >> 5, quad = (c0 >> 3) & 3, j = c0 & 7;
    const int lane  = nl | (quad << 4);
    union { short s4[4]; uint2 u2; } pk;
    pk.s4[0] = f32_to_bf16_rne(v.x);
    pk.s4[1] = f32_to_bf16_rne(v.y);
    pk.s4[2] = f32_to_bf16_rne(v.z);
    pk.s4[3] = f32_to_bf16_rne(v.w);
    *(uint2*)(bsw + ((T * 2 + chunk) * 64 + lane) * 8 + j) = pk.u2;
}

// Main: block = 64 positions, 4 waves. Wave pair (w>>1) owns 32 positions;
// wave (w&1) scans half the codebook (32 tiles of 16 codes). Packed-uint
// argmin: u = (bits(h - dot) & ~0x3FF) | code_id  (positive floats: uint
// order == float order; low bits give first-index tie-break).
__global__ __launch_bounds__(256, 4) void vq_mfma_kernel(
        const float* __restrict__ inp,
        const float* __restrict__ emb,
        const short* __restrict__ bsw,
        const float* __restrict__ hnb,
        float* __restrict__ out,
        float* __restrict__ loss_out) {
    __shared__ unsigned s_red[4][32];
    __shared__ int      s_idx[64];
    __shared__ float    s_wsum[4];

    const int tid    = threadIdx.x;
    const int w      = tid >> 6;
    const int lane   = tid & 63;
    const int lanelo = lane & 15;
    const int quad   = lane >> 4;
    const int ph     = w >> 1;          // which 32-position group
    const int wk     = w & 1;           // which codebook half
    const int pb     = blockIdx.x * 64 + ph * 32;

    // ---- A fragments: 2 M-tiles x 2 K-chunks. A[m=lane&15][k=quad*8+j]. ----
    short8 a[2][2];
#pragma unroll
    for (int t = 0; t < 2; ++t) {
        const int p = pb + t * 16 + lanelo;
        const float* xp = inp + (p >> 12) * CHW + (p & 4095);
#pragma unroll
        for (int chunk = 0; chunk < 2; ++chunk)
#pragma unroll
            for (int j = 0; j < 8; ++j) {
                int c = chunk * 32 + quad * 8 + j;
                a[t][chunk][j] = f32_to_bf16_rne(xp[c * HW]);
            }
    }

    unsigned best[2][4];
#pragma unroll
    for (int t = 0; t < 2; ++t)
#pragma unroll
        for (int r = 0; r < 4; ++r) best[t][r] = 0xFFFFFFFFu;

    // ---- k-loop: 32 tiles of 16 codes ----
    int kn = wk * 512 + lanelo;                       // this lane's code id
    const short* bp = bsw + (size_t)(wk * 32) * 128 * 8;
#pragma unroll 4
    for (int T = 0; T < 32; ++T) {
        const short8 b0 = *(const short8*)(bp + lane * 8);
        const short8 b1 = *(const short8*)(bp + (64 + lane) * 8);
        const float  h  = hnb[kn];
        f32x4 acc0 = {0.f, 0.f, 0.f, 0.f};
        f32x4 acc1 = {0.f, 0.f, 0.f, 0.f};
        acc0 = __builtin_amdgcn_mfma_f32_16x16x32_bf16(a[0][0], b0, acc0, 0, 0, 0);
        acc0 = __builtin_amdgcn_mfma_f32_16x16x32_bf16(a[0][1], b1, acc0, 0, 0, 0);
        acc1 = __builtin_amdgcn_mfma_f32_16x16x32_bf16(a[1][0], b0, acc1, 0, 0, 0);
        acc1 = __builtin_amdgcn_mfma_f32_16x16x32_bf16(a[1][1], b1, acc1, 0, 0, 0);
#pragma unroll
        for (int r = 0; r < 4; ++r) {
            unsigned u0 = (__float_as_uint(h - acc0[r]) & ~1023u) | (unsigned)kn;
            if (u0 < best[0][r]) best[0][r] = u0;
            unsigned u1 = (__float_as_uint(h - acc1[r]) & ~1023u) | (unsigned)kn;
            if (u1 < best[1][r]) best[1][r] = u1;
        }
        kn += 16;
        bp += 128 * 8;
    }

    // ---- cross-lane min over the 16 codes (lanelo bits), then LDS merge ----
#pragma unroll
    for (int t = 0; t < 2; ++t)
#pragma unroll
        for (int r = 0; r < 4; ++r) {
            unsigned b = best[t][r];
#pragma unroll
            for (int m = 1; m < 16; m <<= 1) {
                unsigned o = __shfl_xor(b, m, 64);
                if (o < b) b = o;
            }
            if (lanelo == 0)
                s_red[w][t * 16 + quad * 4 + r] = b;  // C/D row = quad*4+r
        }
    __syncthreads();

    if (tid < 64) {                                   // merge codebook halves
        const int g = tid >> 5, i = tid & 31;
        unsigned u0 = s_red[g * 2 + 0][i];
        unsigned u1 = s_red[g * 2 + 1][i];
        s_idx[tid] = (int)((u0 < u1 ? u0 : u1) & 1023u);
    }
    __syncthreads();

    // ---- epilogue: gather exact fp32 code rows, write [B,C,H,W], loss ----
    const int pos = tid & 63;
    const int c0  = (tid >> 6) * 16;
    const int p   = blockIdx.x * 64 + pos;
    const int b   = p >> 12, hw = p & 4095;
    const int myk = s_idx[pos];
    const float4* er4 = reinterpret_cast<const float4*>(emb + myk * EDIM + c0);
    const float*  xr   = inp + b * CHW + hw;
    float*        orow = out + b * CHW + hw;
    float part = 0.0f;
#pragma unroll
    for (int i4 = 0; i4 < 4; ++i4) {
        float4 q4 = er4[i4];
        int c = c0 + i4 * 4;
        float d;
        d = q4.x - xr[(c + 0) * HW]; part = fmaf(d, d, part); orow[(c + 0) * HW] = q4.x;
        d = q4.y - xr[(c + 1) * HW]; part = fmaf(d, d, part); orow[(c + 1) * HW] = q4.y;
        d = q4.z - xr[(c + 2) * HW]; part = fmaf(d, d, part); orow[(c + 2) * HW] = q4.z;
        d = q4.w - xr[(c + 3) * HW]; part = fmaf(d, d, part); orow[(c + 3) * HW] = q4.w;
    }

#pragma unroll
    for (int off = 32; off > 0; off >>= 1)
        part += __shfl_down(part, off, 64);
    if (lane == 0) s_wsum[w] = part;
    __syncthreads();
    if (tid == 0) {
        float s = (s_wsum[0] + s_wsum[1]) + (s_wsum[2] + s_wsum[3]);
        atomicAdd(loss_out, s * (1.25f / (float)NOUT));
    }
}

extern "C" void kernel_launch(void* const* d_in, const int* in_sizes, int n_in,
                              void* d_out, int out_size, void* d_ws, size_t ws_size,
                              hipStream_t stream) {
    const float* inp = (const float*)d_in[0];    // [16,64,64,64] fp32
    const float* emb = (const float*)d_in[1];    // [1024,64] fp32
    float* out  = (float*)d_out;                 // 4194304 quantized + 1 loss
    float* loss = out + NOUT;

    short* bsw = (short*)d_ws;                           // 128 KiB bf16 swizzled B
    float* hnb = (float*)((char*)d_ws + 131072);         // 4 KiB biased half-norms

    vq_prep_kernel<<<64, 256, 0, stream>>>(emb, bsw, hnb, loss);
    vq_mfma_kernel<<<NPOS / 64, 256, 0, stream>>>(inp, emb, bsw, hnb, out, loss);
}

// Round 4
// 94.775 us; speedup vs baseline: 5.2400x; 1.0120x over previous
//
#include <hip/hip_runtime.h>

#define NUM_EMB 1024
#define EDIM 64
#define HW 4096      // 64*64 spatial
#define CHW 262144   // 64 ch * 4096
#define NPOS 65536   // 16 * 4096 positions
#define NOUT 4194304 // output elements (excl. loss scalar)

typedef __attribute__((ext_vector_type(8))) short short8;   // 8 bf16 = 4 VGPRs
typedef __attribute__((ext_vector_type(4))) float f32x4;

__device__ inline short f32_to_bf16_rne(float f) {
    unsigned u = __float_as_uint(f);
    unsigned r = (u + 0x7fffu + ((u >> 16) & 1u)) >> 16;
    return (short)r;
}

// Prep: codebook -> bf16 swizzled B-fragments + biased half-norms + zero loss.
// B-frag (16x16x32): lane=(n&15)|(quad<<4) holds B[n][chunk*32+quad*8+j], j=0..7.
__global__ void vq_prep_kernel(const float* __restrict__ emb,
                               short* __restrict__ bsw,
                               float* __restrict__ hnb,
                               float* __restrict__ loss_out) {
    const int gid = blockIdx.x * 256 + threadIdx.x;   // 0..16383
    if (gid == 0) *loss_out = 0.0f;
    const int k  = gid >> 4;          // code id
    const int c0 = (gid & 15) * 4;    // channel group base
    float4 v = *(const float4*)(emb + k * EDIM + c0);
    float s = v.x * v.x + v.y * v.y + v.z * v.z + v.w * v.w;
#pragma unroll
    for (int m = 1; m < 16; m <<= 1) s += __shfl_xor(s, m, 64);
    if (c0 == 0) hnb[k] = 0.5f * s + 0.25f;           // bias -> scores positive

    const int T = k >> 4, nl = k & 15;
    const int chunk = c0 >> 5, quad = (c0 >> 3) & 3, j = c0 & 7;
    const int lane  = nl | (quad << 4);
    union { short s4[4]; uint2 u2; } pk;
    pk.s4[0] = f32_to_bf16_rne(v.x);
    pk.s4[1] = f32_to_bf16_rne(v.y);
    pk.s4[2] = f32_to_bf16_rne(v.z);
    pk.s4[3] = f32_to_bf16_rne(v.w);
    *(uint2*)(bsw + ((T * 2 + chunk) * 64 + lane) * 8 + j) = pk.u2;
}

// Main: block = 64 positions, 4 waves. ALL waves hold the same 64 positions
// (4 M-tiles of 16); wave w scans codebook quarter w (16 tiles of 16 codes).
// Each pair of B-fragment loads feeds 8 MFMAs (4 M-tiles x 2 K-chunks).
// Packed-uint argmin: u = (bits(h - dot) & ~0x3FF) | code_id (scores biased
// positive -> uint order == float order; low bits = first-index tie-break).
__global__ __launch_bounds__(256, 4) void vq_mfma_kernel(
        const float* __restrict__ inp,
        const float* __restrict__ emb,
        const short* __restrict__ bsw,
        const float* __restrict__ hnb,
        float* __restrict__ out,
        float* __restrict__ loss_out) {
    __shared__ unsigned s_red[4][64];
    __shared__ int      s_idx[64];
    __shared__ float    s_wsum[4];

    const int tid    = threadIdx.x;
    const int w      = tid >> 6;        // wave id = codebook quarter
    const int lane   = tid & 63;
    const int lanelo = lane & 15;
    const int quad   = lane >> 4;
    const int pb     = blockIdx.x * 64;

    // ---- A fragments: 4 M-tiles x 2 K-chunks. A[m=lane&15][k=quad*8+j]. ----
    short8 a[4][2];
#pragma unroll
    for (int t = 0; t < 4; ++t) {
        const int p = pb + t * 16 + lanelo;
        const float* xp = inp + (p >> 12) * CHW + (p & 4095);
#pragma unroll
        for (int chunk = 0; chunk < 2; ++chunk)
#pragma unroll
            for (int j = 0; j < 8; ++j) {
                int c = chunk * 32 + quad * 8 + j;
                a[t][chunk][j] = f32_to_bf16_rne(xp[c * HW]);
            }
    }

    unsigned best[4][4];
#pragma unroll
    for (int t = 0; t < 4; ++t)
#pragma unroll
        for (int r = 0; r < 4; ++r) best[t][r] = 0xFFFFFFFFu;

    // ---- k-loop: 16 tiles of 16 codes (this wave's quarter) ----
    int kn = w * 256 + lanelo;                        // this lane's code id
    const short* bp = bsw + (size_t)(w * 16) * 128 * 8;
#pragma unroll 2
    for (int T = 0; T < 16; ++T) {
        const short8 b0 = *(const short8*)(bp + lane * 8);
        const short8 b1 = *(const short8*)(bp + (64 + lane) * 8);
        const float  h  = hnb[kn];
        f32x4 acc[4];
#pragma unroll
        for (int t = 0; t < 4; ++t) acc[t] = (f32x4){0.f, 0.f, 0.f, 0.f};
#pragma unroll
        for (int t = 0; t < 4; ++t) {
            acc[t] = __builtin_amdgcn_mfma_f32_16x16x32_bf16(a[t][0], b0, acc[t], 0, 0, 0);
            acc[t] = __builtin_amdgcn_mfma_f32_16x16x32_bf16(a[t][1], b1, acc[t], 0, 0, 0);
        }
#pragma unroll
        for (int t = 0; t < 4; ++t)
#pragma unroll
            for (int r = 0; r < 4; ++r) {
                unsigned u = (__float_as_uint(h - acc[t][r]) & ~1023u) | (unsigned)kn;
                if (u < best[t][r]) best[t][r] = u;
            }
        kn += 16;
        bp += 128 * 8;
    }

    // ---- cross-lane min over the 16 codes (lanelo bits), stash per wave ----
#pragma unroll
    for (int t = 0; t < 4; ++t)
#pragma unroll
        for (int r = 0; r < 4; ++r) {
            unsigned b = best[t][r];
#pragma unroll
            for (int m = 1; m < 16; m <<= 1) {
                unsigned o = __shfl_xor(b, m, 64);
                if (o < b) b = o;
            }
            if (lanelo == 0)
                s_red[w][t * 16 + quad * 4 + r] = b;  // C/D row = quad*4+r
        }
    __syncthreads();

    if (tid < 64) {                                   // merge 4 codebook quarters
        unsigned u0 = s_red[0][tid], u1 = s_red[1][tid];
        unsigned u2 = s_red[2][tid], u3 = s_red[3][tid];
        unsigned m01 = u0 < u1 ? u0 : u1;
        unsigned m23 = u2 < u3 ? u2 : u3;
        s_idx[tid] = (int)((m01 < m23 ? m01 : m23) & 1023u);
    }
    __syncthreads();

    // ---- epilogue: gather exact fp32 code rows, write [B,C,H,W], loss ----
    const int pos = tid & 63;
    const int c0  = (tid >> 6) * 16;
    const int p   = pb + pos;
    const int b   = p >> 12, hw = p & 4095;
    const int myk = s_idx[pos];
    const float4* er4 = reinterpret_cast<const float4*>(emb + myk * EDIM + c0);
    const float*  xr   = inp + b * CHW + hw;
    float*        orow = out + b * CHW + hw;
    float part = 0.0f;
#pragma unroll
    for (int i4 = 0; i4 < 4; ++i4) {
        float4 q4 = er4[i4];
        int c = c0 + i4 * 4;
        float d;
        d = q4.x - xr[(c + 0) * HW]; part = fmaf(d, d, part); orow[(c + 0) * HW] = q4.x;
        d = q4.y - xr[(c + 1) * HW]; part = fmaf(d, d, part); orow[(c + 1) * HW] = q4.y;
        d = q4.z - xr[(c + 2) * HW]; part = fmaf(d, d, part); orow[(c + 2) * HW] = q4.z;
        d = q4.w - xr[(c + 3) * HW]; part = fmaf(d, d, part); orow[(c + 3) * HW] = q4.w;
    }

#pragma unroll
    for (int off = 32; off > 0; off >>= 1)
        part += __shfl_down(part, off, 64);
    if (lane == 0) s_wsum[w] = part;
    __syncthreads();
    if (tid == 0) {
        float s = (s_wsum[0] + s_wsum[1]) + (s_wsum[2] + s_wsum[3]);
        atomicAdd(loss_out, s * (1.25f / (float)NOUT));
    }
}

extern "C" void kernel_launch(void* const* d_in, const int* in_sizes, int n_in,
                              void* d_out, int out_size, void* d_ws, size_t ws_size,
                              hipStream_t stream) {
    const float* inp = (const float*)d_in[0];    // [16,64,64,64] fp32
    const float* emb = (const float*)d_in[1];    // [1024,64] fp32
    float* out  = (float*)d_out;                 // 4194304 quantized + 1 loss
    float* loss = out + NOUT;

    short* bsw = (short*)d_ws;                           // 128 KiB bf16 swizzled B
    float* hnb = (float*)((char*)d_ws + 131072);         // 4 KiB biased half-norms

    vq_prep_kernel<<<64, 256, 0, stream>>>(emb, bsw, hnb, loss);
    vq_mfma_kernel<<<NPOS / 64, 256, 0, stream>>>(inp, emb, bsw, hnb, out, loss);
}